// Round 6
// baseline (350.395 us; speedup 1.0000x reference)
//
#include <hip/hip_runtime.h>
#include <math.h>

#define NUM_KV_HEADS 8
#define HEAD_DIM 128
#define HD (NUM_KV_HEADS * HEAD_DIM)    // 1024 floats = 4 KB token row
#define BLOCK_SZ 16
#define MODEL_CTX 4096
#define TC 32                            // tokens per workgroup chunk
#define NEG_BIG (-1e30f)

// Kernel 0: rope cos/sin table by absolute position.
// tab[t*128 + 2f] = cos(t*invf_f), tab[t*128 + 2f+1] = sin(t*invf_f), f=0..63.
__global__ void rope_table(float* __restrict__ tab, int ntab) {
    const int idx = blockIdx.x * 256 + threadIdx.x;   // t*64 + f
    if (idx >= ntab * 64) return;
    const int t = idx >> 6;
    const int f = idx & 63;
    const float inv = expf(-9.210340371976184f * (float)f * (1.0f / 64.0f));
    float s, c;
    sincosf((float)t * inv, &s, &c);
    tab[2 * idx]     = c;
    tab[2 * idx + 1] = s;
}

// Kernel 1: workgroup = (b, 32-token chunk). The block's 8 half-waves = the 8
// heads; all walk the SAME token loop, so their per-token loads jointly cover
// the full contiguous 4-KB K/V rows -> sequential DRAM bursts. Per half-wave:
// lane=dim (coalesced float2), 4-token batches with a 2-deep pipeline,
// overlapped shuffle reductions, online softmax. No LDS, no __syncthreads;
// raw s_barrier keeps waves convergent for row-merged fetches.
__global__ __launch_bounds__(256, 4)
void attn_partial(const float* __restrict__ q,
                  const float* __restrict__ knew,
                  const float* __restrict__ vnew,
                  const float* __restrict__ kcache,
                  const float* __restrict__ vcache,
                  const int* __restrict__ btab,
                  const int* __restrict__ seqlen_p,
                  const float* __restrict__ tab,
                  int nbps,
                  float* __restrict__ o_part,    // [B*H][n_chunks][128]
                  float* __restrict__ m_part,
                  float* __restrict__ l_part,
                  int n_chunks)
{
    const int chunk = blockIdx.x;
    const int b     = blockIdx.y;
    const int tid   = threadIdx.x;
    const int wave  = tid >> 6;
    const int lane  = tid & 63;
    const int sl    = lane & 31;
    const int half  = lane >> 5;
    const int hw    = wave * 2 + half;     // head 0..7
    const int bh    = b * NUM_KV_HEADS + hw;

    const int seq_len = *seqlen_p;
    const int rem = (seq_len - 1) & (BLOCK_SZ - 1);
    const int T   = (nbps - 1) * BLOCK_SZ + rem + 1;
    const int Tm1 = T - 1;

    // roped q for this head (pos MODEL_CTX-1)
    const float* qb = q + (size_t)bh * HEAD_DIM;
    const float2 qa  = *(const float2*)(qb + 2 * sl);
    const float2 qb2 = *(const float2*)(qb + 64 + 2 * sl);
    const float4 qcs = *(const float4*)(tab + (size_t)(MODEL_CTX - 1) * 128 + 4 * sl);
    const float qr0 = qa.x * qcs.x - qb2.x * qcs.y;
    const float qr1 = qa.y * qcs.z - qb2.y * qcs.w;
    const float qr2 = qb2.x * qcs.x + qa.x * qcs.y;
    const float qr3 = qb2.y * qcs.z + qa.y * qcs.w;

    const float* knb = knew + (size_t)bh * HEAD_DIM;
    const float* vnb = vnew + (size_t)bh * HEAD_DIM;
    const int t0 = chunk * TC;
    const float scale = 0.08838834764831845f;   // 1/sqrt(128)

    float m = NEG_BIG, l = 0.f;
    float a0 = 0.f, a1 = 0.f, a2 = 0.f, a3 = 0.f;

    struct Batch { float2 k1[4], k2[4], v1[4], v2[4]; float4 cs[4]; };

    auto load_batch = [&](Batch& B, int tb) {
        #pragma unroll
        for (int u = 0; u < 4; u++) {
            const int t = tb + u;                 // wave-uniform
            const float* kp;
            const float* vp;
            int tt;
            if (t >= Tm1) { kp = knb; vp = vnb; tt = MODEL_CTX - 1; }
            else {
                const int blkid = btab[b * nbps + (t >> 4)];
                const size_t row = (size_t)blkid * BLOCK_SZ + (t & 15);
                kp = kcache + row * HD + hw * HEAD_DIM;
                vp = vcache + row * HD + hw * HEAD_DIM;
                tt = t;
            }
            B.k1[u] = *(const float2*)(kp + 2 * sl);
            B.k2[u] = *(const float2*)(kp + 64 + 2 * sl);
            B.v1[u] = *(const float2*)(vp + 2 * sl);
            B.v2[u] = *(const float2*)(vp + 64 + 2 * sl);
            B.cs[u] = *(const float4*)(tab + (size_t)tt * 128 + 4 * sl);
        }
    };

    auto compute_batch = [&](const Batch& B, int tb) {
        float d[4];
        #pragma unroll
        for (int u = 0; u < 4; u++) {
            const float r0 = B.k1[u].x * B.cs[u].x - B.k2[u].x * B.cs[u].y;
            const float r1 = B.k1[u].y * B.cs[u].z - B.k2[u].y * B.cs[u].w;
            const float r2 = B.k2[u].x * B.cs[u].x + B.k1[u].x * B.cs[u].y;
            const float r3 = B.k2[u].y * B.cs[u].z + B.k1[u].y * B.cs[u].w;
            d[u] = r0 * qr0 + r1 * qr1 + r2 * qr2 + r3 * qr3;
        }
        // four independent 5-step reductions, interleaved (chains overlap)
        #pragma unroll
        for (int off = 1; off < 32; off <<= 1) {
            #pragma unroll
            for (int u = 0; u < 4; u++) d[u] += __shfl_xor(d[u], off, 64);
        }
        float s[4];
        #pragma unroll
        for (int u = 0; u < 4; u++)
            s[u] = (tb + u < T) ? d[u] * scale : NEG_BIG;
        const float mb = fmaxf(fmaxf(s[0], s[1]), fmaxf(s[2], s[3]));
        const float m_new = fmaxf(m, mb);
        if (m_new <= NEG_BIG) return;            // fully-masked batch
        const float alpha = (m <= NEG_BIG) ? 0.f : __expf(m - m_new);
        float p[4];
        #pragma unroll
        for (int u = 0; u < 4; u++)
            p[u] = (s[u] <= NEG_BIG) ? 0.f : __expf(s[u] - m_new);
        l  = l  * alpha + (p[0] + p[1] + p[2] + p[3]);
        a0 = a0 * alpha + p[0]*B.v1[0].x + p[1]*B.v1[1].x + p[2]*B.v1[2].x + p[3]*B.v1[3].x;
        a1 = a1 * alpha + p[0]*B.v1[0].y + p[1]*B.v1[1].y + p[2]*B.v1[2].y + p[3]*B.v1[3].y;
        a2 = a2 * alpha + p[0]*B.v2[0].x + p[1]*B.v2[1].x + p[2]*B.v2[2].x + p[3]*B.v2[3].x;
        a3 = a3 * alpha + p[0]*B.v2[0].y + p[1]*B.v2[1].y + p[2]*B.v2[2].y + p[3]*B.v2[3].y;
        m = m_new;
    };

    // 2-deep software pipeline over 8 batches of 4 tokens
    Batch B0, B1;
    load_batch(B0, t0);
    #pragma unroll
    for (int i = 0; i < TC / 4; i++) {
        __builtin_amdgcn_s_barrier();            // keep waves' streams convergent
        if (i + 1 < TC / 4) {
            if (i & 1) load_batch(B0, t0 + 4 * (i + 1));
            else       load_batch(B1, t0 + 4 * (i + 1));
        }
        if (i & 1) compute_batch(B1, t0 + 4 * i);
        else       compute_batch(B0, t0 + 4 * i);
    }

    // direct per-head writeout (no block combine needed)
    float* op = o_part + ((size_t)bh * n_chunks + chunk) * HEAD_DIM;
    *(float2*)(op + 2 * sl)      = make_float2(a0, a1);
    *(float2*)(op + 64 + 2 * sl) = make_float2(a2, a3);
    if (sl == 0) {
        m_part[bh * n_chunks + chunk] = m;
        l_part[bh * n_chunks + chunk] = l;
    }
}

// Kernel 2: combine split-K partials.
__global__ void attn_combine(const float* __restrict__ o_part,
                             const float* __restrict__ m_part,
                             const float* __restrict__ l_part,
                             float* __restrict__ out,
                             int n_chunks)
{
    const int bh = blockIdx.x;
    const int d  = threadIdx.x;

    float M = -INFINITY;
    for (int c = 0; c < n_chunks; c++) M = fmaxf(M, m_part[bh * n_chunks + c]);
    float L = 0.f, num = 0.f;
    for (int c = 0; c < n_chunks; c++) {
        const float w = __expf(m_part[bh * n_chunks + c] - M);
        L   += l_part[bh * n_chunks + c] * w;
        num += w * o_part[((size_t)bh * n_chunks + c) * HEAD_DIM + d];
    }
    out[(size_t)bh * HEAD_DIM + d] = num / L;
}

extern "C" void kernel_launch(void* const* d_in, const int* in_sizes, int n_in,
                              void* d_out, int out_size, void* d_ws, size_t ws_size,
                              hipStream_t stream) {
    const float* q  = (const float*)d_in[0];
    const float* k  = (const float*)d_in[1];
    const float* v  = (const float*)d_in[2];
    const float* kc = (const float*)d_in[3];
    const float* vc = (const float*)d_in[4];
    const int* bt   = (const int*)d_in[5];
    const int* slp  = (const int*)d_in[7];

    const int B    = in_sizes[0] / HD;
    const int nbps = in_sizes[5] / B;                     // 256
    const int n_chunks = (nbps * BLOCK_SZ) / TC;          // 128
    const int BH = B * NUM_KV_HEADS;

    int ntab = nbps * BLOCK_SZ;
    if (ntab < MODEL_CTX) ntab = MODEL_CTX;

    float* tab    = (float*)d_ws;                          // ntab*128 floats
    float* o_part = tab + (size_t)ntab * 128;
    float* m_part = o_part + (size_t)BH * n_chunks * HEAD_DIM;
    float* l_part = m_part + (size_t)BH * n_chunks;

    rope_table<<<(ntab * 64 + 255) / 256, 256, 0, stream>>>(tab, ntab);

    dim3 g1(n_chunks, B);
    attn_partial<<<g1, 256, 0, stream>>>(q, k, v, kc, vc, bt, slp, tab, nbps,
                                         o_part, m_part, l_part, n_chunks);
    attn_combine<<<dim3(BH), HEAD_DIM, 0, stream>>>(o_part, m_part, l_part,
                                                    (float*)d_out, n_chunks);
}